// Round 1
// baseline (462.434 us; speedup 1.0000x reference)
//
#include <hip/hip_runtime.h>
#include <hip/hip_bf16.h>

#define B_ 8
#define H_ 8
#define S_ 1024
#define D_ 64

typedef __attribute__((ext_vector_type(8))) short bf16x8;
typedef __attribute__((ext_vector_type(4))) short bf16x4;
typedef __attribute__((ext_vector_type(4))) float f32x4;

__device__ __forceinline__ short f2bf(float f) {
  union { float f; unsigned u; } x; x.f = f;
  unsigned r = (x.u + 0x7FFFu + ((x.u >> 16) & 1u)) >> 16;
  return (short)r;
}

// ---------------- pre-pass 1: Q and K f32 -> bf16 in one launch ----------------
__global__ __launch_bounds__(256) void cvt_qk(const float* __restrict__ Q,
                                              const float* __restrict__ K,
                                              short* __restrict__ Qb,
                                              short* __restrict__ Kb) {
  const float* in = blockIdx.y ? K : Q;
  short* out      = blockIdx.y ? Kb : Qb;
  const size_t i = ((size_t)blockIdx.x * 256 + threadIdx.x) * 8;
  float4 a = *(const float4*)(in + i);
  float4 b = *(const float4*)(in + i + 4);
  bf16x8 f;
  f[0] = f2bf(a.x); f[1] = f2bf(a.y); f[2] = f2bf(a.z); f[3] = f2bf(a.w);
  f[4] = f2bf(b.x); f[5] = f2bf(b.y); f[6] = f2bf(b.z); f[7] = f2bf(b.w);
  *(bf16x8*)(out + i) = f;
}

// ------------- pre-pass 2: V[bh][s][d] f32 -> Vt[bh][d][s] bf16 -------------
__global__ __launch_bounds__(256) void vtrans(const float* __restrict__ V,
                                              short* __restrict__ Vt) {
  const int bh = blockIdx.y;
  const int s0 = blockIdx.x * 64;
  __shared__ float tile[64][65];
  const float* Vb = V + ((size_t)bh * S_ + s0) * D_;
  const int t = threadIdx.x;
  {
    const int rbase = t >> 4;
    const int c4 = (t & 15) * 4;
    #pragma unroll
    for (int i = 0; i < 4; ++i) {
      const int row = i * 16 + rbase;
      float4 v = *(const float4*)(Vb + (size_t)row * D_ + c4);
      tile[row][c4 + 0] = v.x; tile[row][c4 + 1] = v.y;
      tile[row][c4 + 2] = v.z; tile[row][c4 + 3] = v.w;
    }
  }
  __syncthreads();
  const int d = t >> 2;
  const int sq = (t & 3) * 16;
  short* op = Vt + ((size_t)bh * D_ + d) * S_ + s0 + sq;
  bf16x8 a, b;
  #pragma unroll
  for (int j = 0; j < 8; ++j) {
    a[j] = f2bf(tile[sq + j][d]);
    b[j] = f2bf(tile[sq + 8 + j][d]);
  }
  *(bf16x8*)op = a;
  *(bf16x8*)(op + 8) = b;
}

// ------------------------------ main kernel --------------------------------
// Swapped-operand scores: D[k][q] -> lane holds q = lane&15 (fixed),
// k = kt*16 + quad*4 + r. Softmax reduction is 2 shuffles + LDS cross-wave.
// A-write is dwordx4 nontemporal. P stays in registers and feeds
// mfma_f32_16x16x16_bf16 (A-frag layout A[m][quad*4+j] == our ownership).
constexpr int QT  = 16;             // q rows per workgroup
constexpr int NW  = 4;              // waves per workgroup
constexpr int TPW = (S_ / 16) / NW; // 16 k-tiles per wave

__global__ __launch_bounds__(256, 4) void attn_fused(
    const short* __restrict__ Qb16, const short* __restrict__ Kb16,
    const short* __restrict__ Vt,
    float* __restrict__ O, float* __restrict__ A)
{
  // XCD-aware swizzle: 4096 blocks, 4096 % 8 == 0 -> bijective.
  const int nwg = (S_ / QT) * B_ * H_;     // 4096
  const int cpx = nwg / 8;                 // 512
  const int lin = blockIdx.x;
  const int swz = (lin & 7) * cpx + (lin >> 3);
  const int bh  = swz / (S_ / QT);
  const int q0  = (swz % (S_ / QT)) * QT;

  const int tid  = threadIdx.x;
  const int wave = tid >> 6;
  const int lane = tid & 63;
  const int m    = lane & 15;
  const int quad = lane >> 4;

  const short* Qb  = Qb16 + (size_t)bh * S_ * D_;
  const short* Kb  = Kb16 + (size_t)bh * S_ * D_;
  const short* Vtb = Vt   + (size_t)bh * D_ * S_;
  float* Ob = O + (size_t)bh * S_ * D_;
  float* Ab = A + (size_t)bh * S_ * S_;

  __shared__ float redmax[NW][QT];
  __shared__ float redsum[NW][QT];
  __shared__ float obuf[NW][QT][D_ + 4];

  // Q fragment (B-operand): lane holds Q[q0+m][quad*8+j]
  bf16x8 qf0, qf1;
  {
    const short* qp = Qb + (size_t)(q0 + m) * D_ + quad * 8;
    qf0 = *(const bf16x8*)qp;
    qf1 = *(const bf16x8*)(qp + 32);
  }

  // ---- scores (raw, unscaled; scale folded into exp2 constant) ----
  f32x4 acc[TPW];
  #pragma unroll
  for (int t = 0; t < TPW; ++t) {
    const int kt = t * NW + wave;
    const short* kp = Kb + (size_t)(kt * 16 + m) * D_ + quad * 8;
    bf16x8 kf0 = *(const bf16x8*)kp;
    bf16x8 kf1 = *(const bf16x8*)(kp + 32);
    f32x4 c = {0.f, 0.f, 0.f, 0.f};
    c = __builtin_amdgcn_mfma_f32_16x16x32_bf16(kf0, qf0, c, 0, 0, 0);
    c = __builtin_amdgcn_mfma_f32_16x16x32_bf16(kf1, qf1, c, 0, 0, 0);
    acc[t] = c;
  }

  // ---- column (q=m) max over all k ----
  float vmax = acc[0][0];
  #pragma unroll
  for (int t = 0; t < TPW; ++t) {
    #pragma unroll
    for (int r = 0; r < 4; ++r) vmax = fmaxf(vmax, acc[t][r]);
  }
  vmax = fmaxf(vmax, __shfl_xor(vmax, 16));
  vmax = fmaxf(vmax, __shfl_xor(vmax, 32));
  if (lane < 16) redmax[wave][lane] = vmax;
  __syncthreads();
  const float gm = fmaxf(fmaxf(redmax[0][m], redmax[1][m]),
                         fmaxf(redmax[2][m], redmax[3][m]));

  // ---- exp + sum (p = exp2((s_raw - gm_raw) * 0.125 * log2e)) ----
  constexpr float CE = 0.125f * 1.4426950408889634f;
  float s = 0.f;
  #pragma unroll
  for (int t = 0; t < TPW; ++t) {
    #pragma unroll
    for (int r = 0; r < 4; ++r) {
      float e = __builtin_exp2f((acc[t][r] - gm) * CE);
      acc[t][r] = e;
      s += e;
    }
  }
  s += __shfl_xor(s, 16);
  s += __shfl_xor(s, 32);
  if (lane < 16) redsum[wave][lane] = s;
  __syncthreads();
  const float rinv = 1.f / ((redsum[0][m] + redsum[1][m]) +
                            (redsum[2][m] + redsum[3][m]));

  // ---- fused: normalize -> A store (dwordx4 NT) -> pack -> PV MFMA ----
  f32x4 oc0 = {0.f,0.f,0.f,0.f}, oc1 = {0.f,0.f,0.f,0.f};
  f32x4 oc2 = {0.f,0.f,0.f,0.f}, oc3 = {0.f,0.f,0.f,0.f};
  #pragma unroll
  for (int t = 0; t < TPW; ++t) {
    const int kt = t * NW + wave;
    f32x4 pn = acc[t] * rinv;
    __builtin_nontemporal_store(pn,
        (f32x4*)&Ab[(size_t)(q0 + m) * S_ + kt * 16 + quad * 4]);
    bf16x4 pa;
    pa[0] = f2bf(pn[0]); pa[1] = f2bf(pn[1]);
    pa[2] = f2bf(pn[2]); pa[3] = f2bf(pn[3]);
    const short* vp = Vtb + (size_t)m * S_ + kt * 16 + quad * 4;
    bf16x4 bv0 = *(const bf16x4*)(vp);
    bf16x4 bv1 = *(const bf16x4*)(vp + (size_t)16 * S_);
    bf16x4 bv2 = *(const bf16x4*)(vp + (size_t)32 * S_);
    bf16x4 bv3 = *(const bf16x4*)(vp + (size_t)48 * S_);
    oc0 = __builtin_amdgcn_mfma_f32_16x16x16bf16_1k(pa, bv0, oc0, 0, 0, 0);
    oc1 = __builtin_amdgcn_mfma_f32_16x16x16bf16_1k(pa, bv1, oc1, 0, 0, 0);
    oc2 = __builtin_amdgcn_mfma_f32_16x16x16bf16_1k(pa, bv2, oc2, 0, 0, 0);
    oc3 = __builtin_amdgcn_mfma_f32_16x16x16bf16_1k(pa, bv3, oc3, 0, 0, 0);
  }

  // ---- cross-wave O reduction via LDS ----
  #pragma unroll
  for (int r = 0; r < 4; ++r) {
    obuf[wave][quad * 4 + r][m]      = oc0[r];
    obuf[wave][quad * 4 + r][16 + m] = oc1[r];
    obuf[wave][quad * 4 + r][32 + m] = oc2[r];
    obuf[wave][quad * 4 + r][48 + m] = oc3[r];
  }
  __syncthreads();
  {
    const int q  = tid >> 4;          // 0..15
    const int d4 = (tid & 15) * 4;    // 0..60
    f32x4 o0 = *(const f32x4*)&obuf[0][q][d4];
    f32x4 o1 = *(const f32x4*)&obuf[1][q][d4];
    f32x4 o2 = *(const f32x4*)&obuf[2][q][d4];
    f32x4 o3 = *(const f32x4*)&obuf[3][q][d4];
    f32x4 o = (o0 + o1) + (o2 + o3);
    *(f32x4*)&Ob[(size_t)(q0 + q) * D_ + d4] = o;
  }
}

extern "C" void kernel_launch(void* const* d_in, const int* in_sizes, int n_in,
                              void* d_out, int out_size, void* d_ws, size_t ws_size,
                              hipStream_t stream) {
  const float* Q = (const float*)d_in[0];
  const float* K = (const float*)d_in[1];
  const float* V = (const float*)d_in[2];
  float* O = (float*)d_out;
  float* A = O + (size_t)B_ * H_ * S_ * D_;

  const size_t NEL = (size_t)B_ * H_ * S_ * D_;  // 4194304
  short* Qbf = (short*)d_ws;
  short* Kbf = Qbf + NEL;
  short* Vtb = Kbf + NEL;

  const int cvt_blocks = (int)(NEL / 8 / 256);   // 2048
  cvt_qk<<<dim3(cvt_blocks, 2), 256, 0, stream>>>(Q, K, Qbf, Kbf);
  vtrans<<<dim3(S_ / 64, B_ * H_), 256, 0, stream>>>(V, Vtb);

  attn_fused<<<(S_ / QT) * B_ * H_, NW * 64, 0, stream>>>(Qbf, Kbf, Vtb, O, A);
}